// Round 2
// baseline (162.986 us; speedup 1.0000x reference)
//
#include <hip/hip_runtime.h>

#define DD 160
#define HH 192
#define WW 160
#define HWs (HH * WW)          // 30720
#define NTOT 9830400.0f        // 2*160*192*160
#define DOUT 20                // output slices per block
#define NIT  28                // DOUT + 8 halo
#define NBLK 960

// ---- SD layout: [parity][row 0..23][g 0..9][ch-slot 0..5] in h4 (8 B) units.
// Row stride 62 (60 data + 2 pad); rows get +2 per 8-row group (bank rotate);
// ch0..3 contiguous -> one b128 write; ch4 at slot 4+(g&1) (bank spread).
// Byte offsets: 62*8=496 and 6*8=48 are multiples of 16 -> b128-aligned.
#define SDRS 62
#define SDP  1492              // parity stride (max idx 1489), even
// ---- HS layout: [parity][ch 0..4][row 0..15][g 0..9] in h4 units.
// Row stride 10: ph3's (hh,sg) lanes land exactly 4 per bank-pair (b64 floor).
#define HSRS 10
#define HSC  162
#define HSP  810

typedef float    v4 __attribute__((ext_vector_type(4)));
typedef _Float16 h4 __attribute__((ext_vector_type(4)));
typedef _Float16 h2 __attribute__((ext_vector_type(2)));
typedef _Float16 h8 __attribute__((ext_vector_type(8)));

// LDS-only barrier: leaves global prefetch loads in flight.
__device__ __forceinline__ void block_sync_lds() {
    __builtin_amdgcn_s_waitcnt(0xc07f);   // vmcnt=63, expcnt=7, lgkmcnt=0
    __builtin_amdgcn_s_barrier();
}
__device__ __forceinline__ v4 up(h4 x) { return __builtin_convertvector(x, v4); }
// packed RTZ downconvert: 2x v_cvt_pkrtz_f16_f32 instead of 4x cvt + packing
__device__ __forceinline__ h4 dnp(v4 x) {
    h2 a = __builtin_bit_cast(h2, __builtin_amdgcn_cvt_pkrtz(x[0], x[1]));
    h2 b = __builtin_bit_cast(h2, __builtin_amdgcn_cvt_pkrtz(x[2], x[3]));
    return __builtin_shufflevector(a, b, 0, 1, 2, 3);
}

// Fully-fused NCC, D-first, ONE barrier per iteration (depth-3 phase pipeline):
//   ph1(t)   rt<240 : rolling 9-window D-sums {I,J,II,JJ,IJ}; 10-deep fp16
//                     reg FIFO; depth-2 global prefetch; 2xb128+1xb64 -> SD[t&1]
//   ph2(t-1) rt<100 : 9-tap + 8-row slide H-sum over SD[(t-1)&1], packed fp16,
//                     initial-window rows kept in regs (16 reads, not 23) -> HS
//   ph3(t-2) rt>=128: sliding W-sum over HS[t&1] + cc, 4 outputs/thread
// Parity audit unchanged from previous version (bar-separated across parities).
// Wave-role swap by block parity spreads ph3-heavy waves across SIMDs.
// LDS 37.9 KB -> 4 blocks/CU.
__global__ __launch_bounds__(256, 4) void kf(const float* __restrict__ I,
                                             const float* __restrict__ J,
                                             float* __restrict__ partial) {
    __shared__ __align__(16) h4 SDL[2 * SDP];   // 23872 B
    __shared__ __align__(16) h4 HSL[2 * HSP];   // 12960 B
    __shared__ float red[256];                  //  1024 B

    const int tid = threadIdx.x;
    const int bx = blockIdx.x, by = blockIdx.y, b = blockIdx.z;
    const int w0 = (bx % 5) * 32, h0 = (bx / 5) * 16;
    const int d0 = by * DOUT;
    const int bid = bx + 60 * (by + 8 * b);

    const int rt = tid ^ ((bx & 1) << 7);   // role swap waves 0,1 <-> 2,3

    // ---- ph1 decode: 240 columns = 24 rows x 10 f4-cols
    const bool p1 = rt < 240;
    const int r = rt / 10, g = rt % 10;
    const int gh = h0 - 4 + r, gw = w0 - 4 + g * 4;   // gw 16B-aligned
    const bool colOK = p1 && gh >= 0 && gh < HH && gw >= 0 && gw < WW;
    const size_t colOff = (size_t)gh * WW + gw;
    const float* Ib = I + (size_t)b * DD * HWs + colOff;
    const float* Jb = J + (size_t)b * DD * HWs + colOff;
    const int sdwOff = r * SDRS + (r >> 3) * 2 + 6 * g;

    // ---- ph2 decode: 100 tasks = 10 f4cols x 5 ch x 2 h-halves (8-row slide)
    const bool p2 = rt < 100;
    const int g2 = rt % 10, ch2 = (rt / 10) % 5, hh0 = (rt / 50) * 8;
    const int sdrOff = hh0 * SDRS + (hh0 >> 3) * 2 + 6 * g2 +
                       (ch2 == 4 ? 4 + (g2 & 1) : ch2);
    const int hswOff = ch2 * HSC + hh0 * HSRS + g2;

    // ---- ph3 decode: 128 tasks = 16 h-rows x 8 w-segments of 4 outputs
    const bool p3 = rt >= 128;
    const int q3 = rt & 127;
    const int hh = q3 >> 3, sg = q3 & 7;
    const int hsrOff = hh * HSRS + sg;

    v4 sd0 = 0.f, sd1 = 0.f, sd2 = 0.f, sd3 = 0.f, sd4 = 0.f;
    h4 fI[10], fJ[10];
#pragma unroll
    for (int uu = 0; uu < 10; ++uu) { fI[uu] = (h4)(_Float16)0; fJ[uu] = (h4)(_Float16)0; }
    v4 pAI = 0.f, pAJ = 0.f, pBI = 0.f, pBJ = 0.f;   // depth-2 prefetch slots
    float acc = 0.f;
    const float inv = 1.0f / 729.0f;

    {   // preload lead slices for t=0 (slot A) and t=1 (slot B)
        const int s0 = d0 - 4;
        if (colOK && s0 >= 0) {
            pAI = *(const v4*)(Ib + (size_t)s0 * HWs);
            pAJ = *(const v4*)(Jb + (size_t)s0 * HWs);
        }
        const int s1 = d0 - 3;
        if (colOK && s1 >= 0) {
            pBI = *(const v4*)(Ib + (size_t)s1 * HWs);
            pBJ = *(const v4*)(Jb + (size_t)s1 * HWs);
        }
    }

    // 30 = NIT+2 iterations exactly; 10-unroll keeps fifo slot (u, (u+1)%10)
    // and prefetch parity (u&1) compile-time constant.
    for (int tb = 0; tb < 30; tb += 10) {
#pragma unroll
        for (int u = 0; u < 10; ++u) {
            const int t = tb + u;

            // ---------- ph1(t): D-rolling, write SD[t&1]
            if (t < NIT && p1) {
                v4 curI, curJ;
                if ((u & 1) == 0) { curI = pAI; curJ = pAJ; }
                else              { curI = pBI; curJ = pBJ; }
                h4 cI = dnp(curI), cJ = dnp(curJ);
                v4 aI = up(cI), aJ = up(cJ);
                v4 dI = aI, dJv = aJ;
                v4 dII = aI * aI, dJJ = aJ * aJ, dIJ = aI * aJ;
                if (t >= 9) {       // retire slice t-9 (fifo slot (u+1)%10)
                    h4 oI = fI[(u + 1) % 10], oJ = fJ[(u + 1) % 10];
                    v4 bI = up(oI), bJ = up(oJ);
                    dI -= bI; dJv -= bJ;
                    dII -= bI * bI; dJJ -= bJ * bJ; dIJ -= bI * bJ;
                }
                fI[u] = cI; fJ[u] = cJ;
                sd0 += dI; sd1 += dJv; sd2 += dII; sd3 += dJJ; sd4 += dIJ;
                h4* const qb = &SDL[(t & 1) * SDP + sdwOff];
                h4 c0 = dnp(sd0), c1 = dnp(sd1), c2 = dnp(sd2), c3 = dnp(sd3);
                *(h8*)qb       = __builtin_shufflevector(c0, c1, 0,1,2,3,4,5,6,7);
                *(h8*)(qb + 2) = __builtin_shufflevector(c2, c3, 0,1,2,3,4,5,6,7);
                qb[4 + (g & 1)] = dnp(sd4);
                // prefetch slice for t+2 into the slot just consumed
                v4 nI = 0.f, nJ = 0.f;
                const int sn = d0 - 2 + t;
                if (t + 2 < NIT && colOK && sn >= 0 && sn < DD) {
                    nI = *(const v4*)(Ib + (size_t)sn * HWs);
                    nJ = *(const v4*)(Jb + (size_t)sn * HWs);
                }
                if ((u & 1) == 0) { pAI = nI; pAJ = nJ; }
                else              { pBI = nI; pBJ = nJ; }
            }

            // ---------- ph2(t-1): H-sums in packed fp16, write HS
            if (t >= 1 && t <= NIT && p2) {
                const int par = (t - 1) & 1;
                const h4* const sdr = &SDL[par * SDP + sdrOff];
                h4* const hsw = &HSL[par * HSP + hswOff];
                h4 keep[7];                 // rows 0..6 of the initial window
                h4 s = sdr[0];
                keep[0] = s;
#pragma unroll
                for (int k = 1; k < 9; ++k) {
                    h4 v = sdr[k * SDRS + (k >= 8 ? 2 : 0)];
                    if (k < 7) keep[k] = v;
                    s += v;
                }
                hsw[0] = s;
#pragma unroll
                for (int j = 1; j < 8; ++j) {
                    s += sdr[(j + 8) * SDRS + 2] - keep[j - 1];
                    hsw[j * HSRS] = s;
                }
            }

            // ---------- ph3(t-2): W-slide + cc (output depth d0+t-10)
            if (t >= 10 && p3) {
                const h4* const hsr = &HSL[(t & 1) * HSP + hsrOff];
                float w[5][4];
#pragma unroll
                for (int c = 0; c < 5; ++c) {
                    v4 fa = up(hsr[c * HSC]);
                    v4 fb = up(hsr[c * HSC + 1]);
                    v4 fc = up(hsr[c * HSC + 2]);
                    float s = fa[0] + fa[1] + fa[2] + fa[3] +
                              fb[0] + fb[1] + fb[2] + fb[3] + fc[0];
                    w[c][0] = s;
                    s += fc[1] - fa[0]; w[c][1] = s;
                    s += fc[2] - fa[1]; w[c][2] = s;
                    s += fc[3] - fa[2]; w[c][3] = s;
                }
#pragma unroll
                for (int e = 0; e < 4; ++e) {
                    float mu1 = w[0][e] * inv, mu2 = w[1][e] * inv;
                    float g1  = fmaf(-mu1, mu1, w[2][e] * inv);
                    float g2v = fmaf(-mu2, mu2, w[3][e] * inv);
                    float g12 = fmaf(-mu1, mu2, w[4][e] * inv);
                    acc += __fdividef(g12 * g12, fmaf(g1, g2v, 1e-5f));
                }
            }

            block_sync_lds();
        }
    }

    red[tid] = acc;     // only p3 threads have nonzero acc
    __syncthreads();
    if (tid < 128) red[tid] += red[tid + 128];
    __syncthreads();
    if (tid < 64) {
        float a = red[tid] + red[tid + 64];
#pragma unroll
        for (int off = 32; off > 0; off >>= 1) a += __shfl_down(a, off);
        if (tid == 0) partial[bid] = a;
    }
}

__global__ void k3_final(const float* __restrict__ partial,
                         float* __restrict__ out) {
    __shared__ float r[1024];
    const int i = threadIdx.x;
    r[i] = (i < NBLK) ? partial[i] : 0.f;
    __syncthreads();
    for (int off = 512; off > 0; off >>= 1) {
        if (i < off) r[i] += r[i + off];
        __syncthreads();
    }
    if (i == 0) out[0] = -r[0] * (1.0f / NTOT);
}

extern "C" void kernel_launch(void* const* d_in, const int* in_sizes, int n_in,
                              void* d_out, int out_size, void* d_ws, size_t ws_size,
                              hipStream_t stream) {
    (void)in_sizes; (void)n_in; (void)out_size; (void)ws_size;
    const float* I = (const float*)d_in[0];   // y_true
    const float* J = (const float*)d_in[1];   // y_pred
    float* out     = (float*)d_out;
    float* partial = (float*)d_ws;            // NBLK floats, all written

    dim3 grid(60, 8, 2);                      // (5w x 12h tiles, D/20, B)
    kf<<<grid, 256, 0, stream>>>(I, J, partial);
    k3_final<<<1, 1024, 0, stream>>>(partial, out);
}